// Round 5
// baseline (1555.497 us; speedup 1.0000x reference)
//
#include <hip/hip_runtime.h>
#include <math.h>

#define H 128
#define EDGES 500000
#define NFACT 100000
#define NCOMP 5000
#define BATCH 64

// ----------------- CSR build -----------------
__global__ void k_hist(const int* __restrict__ dst, int n, int* __restrict__ cnt){
  for (int e = blockIdx.x*blockDim.x + threadIdx.x; e < n; e += gridDim.x*blockDim.x)
    atomicAdd(&cnt[dst[e]], 1);
}

__global__ __launch_bounds__(1024) void k_scan1(const int* __restrict__ cnt, int n,
                                                int* __restrict__ offs, int* __restrict__ part){
  __shared__ int sh[1024];
  int tid = threadIdx.x;
  int i = blockIdx.x*1024 + tid;
  int v = (i < n) ? cnt[i] : 0;
  sh[tid] = v;
  __syncthreads();
  for (int d = 1; d < 1024; d <<= 1){
    int t = (tid >= d) ? sh[tid-d] : 0;
    __syncthreads();
    sh[tid] += t;
    __syncthreads();
  }
  if (i < n) offs[i] = sh[tid] - v;   // exclusive within block
  if (tid == 1023) part[blockIdx.x] = sh[1023];
}

__global__ void k_scan2(int* part, int nb){
  __shared__ int sh[128];
  int tid = threadIdx.x;
  int v = (tid < nb) ? part[tid] : 0;
  sh[tid] = v;
  __syncthreads();
  for (int d = 1; d < 128; d <<= 1){
    int t = (tid >= d) ? sh[tid-d] : 0;
    __syncthreads();
    sh[tid] += t;
    __syncthreads();
  }
  if (tid < nb) part[tid] = sh[tid] - v;  // exclusive block prefix
}

__global__ __launch_bounds__(1024) void k_scan3(int* offs, int n, const int* __restrict__ part, int total){
  int i = blockIdx.x*1024 + threadIdx.x;
  if (i < n) offs[i] += part[blockIdx.x];
  if (i == 0) offs[n] = total;
}

// fill packed per-slot records sorted by dst: {src, w_bits, dst, 0}
__global__ void k_fill2(const int* __restrict__ src, const int* __restrict__ dst,
                        const float* __restrict__ w, int n, const int* __restrict__ offs,
                        int* __restrict__ cur, int4* __restrict__ ed){
  for (int e = blockIdx.x*blockDim.x + threadIdx.x; e < n; e += gridDim.x*blockDim.x){
    int d = dst[e];
    int p = offs[d] + atomicAdd(&cur[d], 1);
    ed[p] = make_int4(src[e], __float_as_int(w[e]), d, 0);
  }
}

// ----------------- edge gate MLP -----------------
__global__ void k_gate(const float* __restrict__ ea,
                       const float* __restrict__ eW1, const float* __restrict__ eb1,
                       const float* __restrict__ eW2, const float* __restrict__ eb2,
                       const float* __restrict__ eW3, const float* __restrict__ eb3,
                       float* __restrict__ wout, int n){
  __shared__ float w1[11*32], b1[32], w2[32*16], b2[16], w3[16];
  __shared__ float b3;
  int tid = threadIdx.x;
  for (int i = tid; i < 11*32; i += blockDim.x) w1[i] = eW1[i];
  for (int i = tid; i < 32;    i += blockDim.x) b1[i] = eb1[i];
  for (int i = tid; i < 32*16; i += blockDim.x) w2[i] = eW2[i];
  for (int i = tid; i < 16;    i += blockDim.x) b2[i] = eb2[i];
  for (int i = tid; i < 16;    i += blockDim.x) w3[i] = eW3[i];
  if (tid == 0) b3 = eb3[0];
  __syncthreads();
  for (int e = blockIdx.x*blockDim.x + tid; e < n; e += gridDim.x*blockDim.x){
    float sent  = fminf(fmaxf(ea[2*e], -1.f), 1.f);
    float decay = ea[2*e+1];
    float dt = fmaxf(-logf(fmaxf(decay, 1e-6f)) * 100.f, 0.f);  // /LAM, LAM=0.01
    float ds = fminf(dt * (1.f/30.f), 12.f);
    float x[11];
    x[0] = sent; x[1] = log1pf(dt);
    x[2] = sinf(ds);     x[3] = sinf(2.f*ds); x[4] = sinf(3.f*ds); x[5] = sinf(4.f*ds);
    x[6] = cosf(ds);     x[7] = cosf(2.f*ds); x[8] = cosf(3.f*ds); x[9] = cosf(4.f*ds);
    x[10] = ds;
    float h1[32];
    #pragma unroll
    for (int j = 0; j < 32; j++){
      float s = b1[j];
      #pragma unroll
      for (int i = 0; i < 11; i++) s += x[i]*w1[i*32+j];
      h1[j] = fmaxf(s, 0.f);
    }
    float o = b3;
    #pragma unroll
    for (int j = 0; j < 16; j++){
      float s = b2[j];
      #pragma unroll
      for (int i = 0; i < 32; i++) s += h1[i]*w2[i*16+j];
      o += fmaxf(s, 0.f)*w3[j];
    }
    wout[e] = 1.f/(1.f + expf(-o));
  }
}

// ----------------- simple input projection (comp side, small) -----------------
template<int K, int R>
__global__ __launch_bounds__(128) void k_input_s(const float* __restrict__ X, const float* __restrict__ W,
                                                 const float* __restrict__ bias, float* __restrict__ Y){
  __shared__ float xs[R*K];
  int t = threadIdx.x;
  long row0 = (long)blockIdx.x * R;
  const float4* src = (const float4*)(X + row0*K);
  float4* d4 = (float4*)xs;
  for (int i = t; i < R*K/4; i += 128) d4[i] = src[i];
  __syncthreads();
  float acc[R];
  #pragma unroll
  for (int r = 0; r < R; r++) acc[r] = 0.f;
  for (int k4 = 0; k4 < K/4; k4++){
    int kb = k4*4;
    float w0 = W[(kb+0)*H+t], w1 = W[(kb+1)*H+t], w2 = W[(kb+2)*H+t], w3 = W[(kb+3)*H+t];
    #pragma unroll
    for (int r = 0; r < R; r++){
      float4 xv = ((const float4*)(xs + r*K))[k4];
      acc[r] += xv.x*w0 + xv.y*w1 + xv.z*w2 + xv.w*w3;
    }
  }
  float b = bias[t];
  #pragma unroll
  for (int r = 0; r < R; r++)
    Y[(row0+r)*H + t] = fmaxf(acc[r] + b, 0.f);
}

// ----------------- tiled input projection (fact side) v4:
// 32 rows x 128 cols / block; 4 groups of 32 lanes, group g owns rows 8g..8g+7.
// 8 rows x 4 cols per thread (FMA : W-load = 32:1). X staged group-locally in
// K-halves (24 KB LDS, no barriers); W float4 read directly from L2.
template<int K>   // K=384
__global__ __launch_bounds__(128) void k_input_t(const float* __restrict__ X, const float* __restrict__ W,
                                                 const float* __restrict__ bias, float* __restrict__ Y){
  constexpr int KH = K/2;            // 192
  __shared__ float xs[32][KH];
  int t = threadIdx.x;
  int c = t & 31, g = t >> 5;
  long row0 = (long)blockIdx.x * 32;
  int gr0 = 8*g;
  float4 acc[8];
  float4 bv = ((const float4*)bias)[c];
  #pragma unroll
  for (int r = 0; r < 8; r++) acc[r] = bv;

  #pragma unroll
  for (int p = 0; p < 2; p++){
    // group-local staging of this K-half (intra-wave LDS ordering; no barriers)
    #pragma unroll
    for (int r = 0; r < 8; r++){
      const float4* s4 = (const float4*)(X + (row0 + gr0 + r)*K + p*KH);
      float4* d4 = (float4*)xs[gr0 + r];
      for (int i = c; i < KH/4; i += 32) d4[i] = s4[i];
    }
    const float4* Wp = (const float4*)W + (size_t)(p*KH)*32 + c;
    #pragma unroll 2
    for (int k4 = 0; k4 < KH/4; k4++){
      float4 xv[8];
      #pragma unroll
      for (int r = 0; r < 8; r++)
        xv[r] = ((const float4*)xs[gr0 + r])[k4];
      #pragma unroll
      for (int kk = 0; kk < 4; kk++){
        float4 wv = Wp[(size_t)(k4*4+kk)*32];
        #pragma unroll
        for (int r = 0; r < 8; r++){
          float xk = (kk==0) ? xv[r].x : (kk==1) ? xv[r].y : (kk==2) ? xv[r].z : xv[r].w;
          acc[r].x += xk*wv.x; acc[r].y += xk*wv.y; acc[r].z += xk*wv.z; acc[r].w += xk*wv.w;
        }
      }
    }
  }
  #pragma unroll
  for (int r = 0; r < 8; r++){
    float4 o;
    o.x = fmaxf(acc[r].x, 0.f); o.y = fmaxf(acc[r].y, 0.f);
    o.z = fmaxf(acc[r].z, 0.f); o.w = fmaxf(acc[r].w, 0.f);
    ((float4*)(Y + (row0 + gr0 + r)*H))[c] = o;
  }
}

// ----------------- unified fused layer v4: barrier-free, RG rows/thread -----
// R rows/block; 4 groups of 32 lanes; group g owns rows [g*R/4,(g+1)*R/4).
// Aggregation gathers into group-local LDS rows; GEMM reads W float4 directly
// from L2. GEMM/LN touch only the group's own rows -> no __syncthreads.
template<int R>
__global__ __launch_bounds__(128) void k_layer(
    const float* __restrict__ xsrc, const float* __restrict__ xprev,
    const int* __restrict__ offs, const int4* __restrict__ ed,
    const float* __restrict__ Wrel, const float* __restrict__ brel,
    const float* __restrict__ Wroot, const float* __restrict__ lnsc,
    const float* __restrict__ lnbi, float* __restrict__ xnext){
  constexpr int RG = R/4;
  __shared__ float xin[R][256];   // [row][ agg 0..127 | prev 128..255 ]
  int t = threadIdx.x, c = t & 31, g = t >> 5;
  long row0 = (long)blockIdx.x * R;
  int grow0 = g*RG;
  // zero agg + stage prev (own rows only)
  #pragma unroll
  for (int j = 0; j < RG; j++){
    int lr = grow0 + j;
    ((float4*)&xin[lr][0])[c] = make_float4(0.f,0.f,0.f,0.f);
    ((float4*)&xin[lr][128])[c] = ((const float4*)(xprev + (row0+lr)*H))[c];
  }
  // aggregate this group's slot range (8-wide pipelined gather)
  int lo = offs[row0 + grow0], hi = offs[row0 + grow0 + RG];
  float4 a = make_float4(0.f,0.f,0.f,0.f);
  int cur = (int)row0 + grow0;
  int idx = lo;
  for (; idx + 8 <= hi; idx += 8){
    int4 m[8];
    #pragma unroll
    for (int j = 0; j < 8; j++) m[j] = ed[idx+j];
    float4 v[8];
    #pragma unroll
    for (int j = 0; j < 8; j++) v[j] = ((const float4*)(xsrc + (long)m[j].x*H))[c];
    #pragma unroll
    for (int j = 0; j < 8; j++){
      float w = __int_as_float(m[j].y);
      if (m[j].z != cur){ ((float4*)&xin[cur-(int)row0][0])[c] = a; a = make_float4(0.f,0.f,0.f,0.f); cur = m[j].z; }
      a.x += v[j].x*w; a.y += v[j].y*w; a.z += v[j].z*w; a.w += v[j].w*w;
    }
  }
  for (; idx < hi; idx++){
    int4 m = ed[idx];
    float4 v = ((const float4*)(xsrc + (long)m.x*H))[c];
    float w = __int_as_float(m.y);
    if (m.z != cur){ ((float4*)&xin[cur-(int)row0][0])[c] = a; a = make_float4(0.f,0.f,0.f,0.f); cur = m.z; }
    a.x += v.x*w; a.y += v.y*w; a.z += v.z*w; a.w += v.w*w;
  }
  if (lo < hi) ((float4*)&xin[cur-(int)row0][0])[c] = a;

  // GEMM: logical K=256 = [agg | prev] x [Wrel ; Wroot], W direct from L2.
  float4 acc[RG];
  float4 bv = ((const float4*)brel)[c];
  #pragma unroll
  for (int j = 0; j < RG; j++) acc[j] = bv;
  #pragma unroll
  for (int p = 0; p < 2; p++){
    const float4* Wp = (const float4*)(p ? Wroot : Wrel) + c;
    #pragma unroll 2
    for (int k4 = 0; k4 < 32; k4++){
      float4 xv[RG];
      #pragma unroll
      for (int j = 0; j < RG; j++)
        xv[j] = ((const float4*)xin[grow0+j])[p*32 + k4];
      #pragma unroll
      for (int kk = 0; kk < 4; kk++){
        float4 wv = Wp[(size_t)(k4*4+kk)*32];
        #pragma unroll
        for (int j = 0; j < RG; j++){
          float xk = (kk==0) ? xv[j].x : (kk==1) ? xv[j].y : (kk==2) ? xv[j].z : xv[j].w;
          acc[j].x += xk*wv.x; acc[j].y += xk*wv.y; acc[j].z += xk*wv.z; acc[j].w += xk*wv.w;
        }
      }
    }
  }
  // epilogue: relu + residual + LN across the row's 32 lanes
  float4 lsc = ((const float4*)lnsc)[c];
  float4 lbi = ((const float4*)lnbi)[c];
  #pragma unroll
  for (int j = 0; j < RG; j++){
    int lr = grow0 + j;
    float4 pv = ((const float4*)&xin[lr][128])[c];
    float4 v;
    v.x = fmaxf(acc[j].x, 0.f) + pv.x;
    v.y = fmaxf(acc[j].y, 0.f) + pv.y;
    v.z = fmaxf(acc[j].z, 0.f) + pv.z;
    v.w = fmaxf(acc[j].w, 0.f) + pv.w;
    float s  = v.x + v.y + v.z + v.w;
    float ss = v.x*v.x + v.y*v.y + v.z*v.z + v.w*v.w;
    #pragma unroll
    for (int mm = 1; mm < 32; mm <<= 1){ s += __shfl_xor(s, mm, 64); ss += __shfl_xor(ss, mm, 64); }
    float mu  = s*(1.f/H);
    float var = ss*(1.f/H) - mu*mu;
    float rstd = rsqrtf(var + 1e-5f);
    float4 o;
    o.x = (v.x - mu)*rstd*lsc.x + lbi.x;
    o.y = (v.y - mu)*rstd*lsc.y + lbi.y;
    o.z = (v.z - mu)*rstd*lsc.z + lbi.z;
    o.w = (v.w - mu)*rstd*lsc.w + lbi.w;
    ((float4*)(xnext + (row0+lr)*H))[c] = o;
  }
}

// ----------------- pooling: parallel chunked accumulation with atomics -----------------
#define PCHUNK 128
#define FBLK ((NFACT + PCHUNK - 1) / PCHUNK)
#define CBLK ((NCOMP + PCHUNK - 1) / PCHUNK)

__global__ __launch_bounds__(128) void k_pool_acc(const float* __restrict__ xf, const float* __restrict__ xc,
                                                  const int* __restrict__ fb, const int* __restrict__ cb,
                                                  float* __restrict__ pooled){
  int t = threadIdx.x;
  int b = blockIdx.x;
  if (b < FBLK){
    int start = b*PCHUNK, end = start + PCHUNK; if (end > NFACT) end = NFACT;
    float s = 0.f; int curb = -1;
    for (int i = start; i < end; i++){
      int bb = fb[i];
      if (bb != curb){
        if (curb >= 0) atomicAdd(&pooled[curb*256 + t], s);
        curb = bb; s = 0.f;
      }
      s += xf[(long)i*H + t];
    }
    if (curb >= 0) atomicAdd(&pooled[curb*256 + t], s);
  } else {
    int bbk = b - FBLK;
    int start = bbk*PCHUNK, end = start + PCHUNK; if (end > NCOMP) end = NCOMP;
    float s = 0.f; int curb = -1;
    for (int i = start; i < end; i++){
      int bb = cb[i];
      if (bb != curb){
        if (curb >= 0) atomicAdd(&pooled[curb*256 + 128 + t], s);
        curb = bb; s = 0.f;
      }
      s += xc[(long)i*H + t];
    }
    if (curb >= 0) atomicAdd(&pooled[curb*256 + 128 + t], s);
  }
}

// ----------------- classifier head -----------------
__device__ inline int lowerb(const int* a, int n, int key){
  int lo = 0, hi = n;
  while (lo < hi){ int m = (lo+hi) >> 1; if (a[m] < key) lo = m+1; else hi = m; }
  return lo;
}

__global__ __launch_bounds__(128) void k_head(const float* __restrict__ pooled,
                                              const int* __restrict__ fb, const int* __restrict__ cb,
                                              const float* __restrict__ Wc1, const float* __restrict__ bc1,
                                              const float* __restrict__ Wc2, const float* __restrict__ bc2,
                                              float* __restrict__ out){
  __shared__ float p[256];
  __shared__ float red[2];
  int t = threadIdx.x, b = blockIdx.x;
  int flo = lowerb(fb, NFACT, b), fhi = lowerb(fb, NFACT, b+1);
  int clo = lowerb(cb, NCOMP, b), chi = lowerb(cb, NCOMP, b+1);
  float fc = (float)((fhi - flo) > 1 ? (fhi - flo) : 1);
  float cc = (float)((chi - clo) > 1 ? (chi - clo) : 1);
  p[t]       = pooled[b*256 + t] / fc;
  p[128 + t] = pooled[b*256 + 128 + t] / cc;
  __syncthreads();
  float acc = bc1[t];
  #pragma unroll 4
  for (int k = 0; k < 256; k++) acc += p[k]*Wc1[k*H + t];
  float h = fmaxf(acc, 0.f)*Wc2[t];
  #pragma unroll
  for (int m = 1; m < 64; m <<= 1) h += __shfl_xor(h, m, 64);
  if ((t & 63) == 0) red[t>>6] = h;
  __syncthreads();
  if (t == 0) out[b] = red[0] + red[1] + bc2[0];
}

extern "C" void kernel_launch(void* const* d_in, const int* in_sizes, int n_in,
                              void* d_out, int out_size, void* d_ws, size_t ws_size,
                              hipStream_t stream){
  const float* x_fact = (const float*)d_in[0];
  const float* x_comp = (const float*)d_in[1];
  const float* ea_f2c = (const float*)d_in[2];
  const float* ea_c2f = (const float*)d_in[3];
  const int* s_f2c   = (const int*)d_in[4];
  const int* dst_f2c = (const int*)d_in[5];
  const int* s_c2f   = (const int*)d_in[6];
  const int* dst_c2f = (const int*)d_in[7];
  const int* fb = (const int*)d_in[8];
  const int* cb = (const int*)d_in[9];
  const float* W_in_f = (const float*)d_in[10];
  const float* b_in_f = (const float*)d_in[11];
  const float* W_in_c = (const float*)d_in[12];
  const float* b_in_c = (const float*)d_in[13];
  const float* eW1 = (const float*)d_in[14]; const float* eb1 = (const float*)d_in[15];
  const float* eW2 = (const float*)d_in[16]; const float* eb2 = (const float*)d_in[17];
  const float* eW3 = (const float*)d_in[18]; const float* eb3 = (const float*)d_in[19];
  const float* W_rel = (const float*)d_in[20]; const float* b_rel = (const float*)d_in[21];
  const float* W_root = (const float*)d_in[22];
  const float* ln_s = (const float*)d_in[23]; const float* ln_b = (const float*)d_in[24];
  const float* Wc1 = (const float*)d_in[25]; const float* bc1 = (const float*)d_in[26];
  const float* Wc2 = (const float*)d_in[27]; const float* bc2 = (const float*)d_in[28];
  float* out = (float*)d_out;

  char* ws = (char*)d_ws;
  size_t off = 0;
  auto alloc = [&](size_t bytes)->char*{ char* p = ws + off; off = (off + bytes + 255) & ~(size_t)255; return p; };
  float* xf0   = (float*)alloc((size_t)NFACT*H*4);
  float* xf1   = (float*)alloc((size_t)NFACT*H*4);
  float* xc0   = (float*)alloc((size_t)NCOMP*H*4);
  float* xc1   = (float*)alloc((size_t)NCOMP*H*4);
  float* w_f2c = (float*)alloc((size_t)EDGES*4);
  float* w_c2f = (float*)alloc((size_t)EDGES*4);
  int4* ed_f2c = (int4*)alloc((size_t)EDGES*16);
  int4* ed_c2f = (int4*)alloc((size_t)EDGES*16);
  int* off_f2c = (int*)alloc((size_t)(NCOMP+1)*4);
  int* cur_f2c = (int*)alloc((size_t)NCOMP*4);
  int* off_c2f = (int*)alloc((size_t)(NFACT+1)*4);
  int* cur_c2f = (int*)alloc((size_t)NFACT*4);
  int* part    = (int*)alloc(128*4);
  float* pooled= (float*)alloc((size_t)BATCH*256*4);

  // --- edge gates first (fill packs them) ---
  k_gate<<<512,256,0,stream>>>(ea_f2c, eW1,eb1,eW2,eb2,eW3,eb3, w_f2c, EDGES);
  k_gate<<<512,256,0,stream>>>(ea_c2f, eW1,eb1,eW2,eb2,eW3,eb3, w_c2f, EDGES);

  // --- CSR f2c (dst in comp space) ---
  hipMemsetAsync(cur_f2c, 0, NCOMP*4, stream);
  k_hist<<<512,256,0,stream>>>(dst_f2c, EDGES, cur_f2c);
  {
    int nb = (NCOMP + 1023)/1024;
    k_scan1<<<nb,1024,0,stream>>>(cur_f2c, NCOMP, off_f2c, part);
    k_scan2<<<1,128,0,stream>>>(part, nb);
    k_scan3<<<nb,1024,0,stream>>>(off_f2c, NCOMP, part, EDGES);
  }
  hipMemsetAsync(cur_f2c, 0, NCOMP*4, stream);
  k_fill2<<<512,256,0,stream>>>(s_f2c, dst_f2c, w_f2c, EDGES, off_f2c, cur_f2c, ed_f2c);

  // --- CSR c2f (dst in fact space) ---
  hipMemsetAsync(cur_c2f, 0, NFACT*4, stream);
  k_hist<<<512,256,0,stream>>>(dst_c2f, EDGES, cur_c2f);
  {
    int nb = (NFACT + 1023)/1024;
    k_scan1<<<nb,1024,0,stream>>>(cur_c2f, NFACT, off_c2f, part);
    k_scan2<<<1,128,0,stream>>>(part, nb);
    k_scan3<<<nb,1024,0,stream>>>(off_c2f, NFACT, part, EDGES);
  }
  hipMemsetAsync(cur_c2f, 0, NFACT*4, stream);
  k_fill2<<<512,256,0,stream>>>(s_c2f, dst_c2f, w_c2f, EDGES, off_c2f, cur_c2f, ed_c2f);

  // --- input projections ---
  k_input_t<384><<<NFACT/32,128,0,stream>>>(x_fact, W_in_f, b_in_f, xf0);
  k_input_s<64,8><<<NCOMP/8,128,0,stream>>>(x_comp, W_in_c, b_in_c, xc0);

  // --- GNN layers ---
  const float* xf_p = xf0; const float* xc_p = xc0;
  float* xf_n = xf1; float* xc_n = xc1;
  for (int l = 0; l < 2; l++){
    const float* Wr0 = W_rel  + (size_t)(l*2+0)*H*H;
    const float* Wr1 = W_rel  + (size_t)(l*2+1)*H*H;
    const float* br0 = b_rel  + (size_t)(l*2+0)*H;
    const float* br1 = b_rel  + (size_t)(l*2+1)*H;
    const float* Wo0 = W_root + (size_t)(l*2+0)*H*H;
    const float* Wo1 = W_root + (size_t)(l*2+1)*H*H;
    k_layer<8><<<NCOMP/8,128,0,stream>>>(xf_p, xc_p, off_f2c, ed_f2c,
                                         Wr0, br0, Wo0, ln_s + H, ln_b + H, xc_n);
    k_layer<32><<<NFACT/32,128,0,stream>>>(xc_p, xf_p, off_c2f, ed_c2f,
                                           Wr1, br1, Wo1, ln_s, ln_b, xf_n);
    const float* tf = xf_p; xf_p = xf_n; xf_n = (float*)tf;
    const float* tc = xc_p; xc_p = xc_n; xc_n = (float*)tc;
  }

  // --- pooling + head ---
  hipMemsetAsync(pooled, 0, (size_t)BATCH*256*4, stream);
  k_pool_acc<<<FBLK + CBLK,128,0,stream>>>(xf_p, xc_p, fb, cb, pooled);
  k_head<<<BATCH,128,0,stream>>>(pooled, fb, cb, Wc1, bc1, Wc2, bc2, out);
}

// Round 6
// 1090.335 us; speedup vs baseline: 1.4266x; 1.4266x over previous
//
#include <hip/hip_runtime.h>
#include <math.h>

#define H 128
#define EDGES 500000
#define NFACT 100000
#define NCOMP 5000
#define BATCH 64

typedef _Float16 half8_t __attribute__((ext_vector_type(8)));
typedef float floatx4 __attribute__((ext_vector_type(4)));

__device__ inline short4 f4_to_h4(float4 v){
  union { short4 s; _Float16 h[4]; } u;
  u.h[0]=(_Float16)v.x; u.h[1]=(_Float16)v.y; u.h[2]=(_Float16)v.z; u.h[3]=(_Float16)v.w;
  return u.s;
}

// ----------------- CSR build -----------------
__global__ void k_hist(const int* __restrict__ dst, int n, int* __restrict__ cnt){
  for (int e = blockIdx.x*blockDim.x + threadIdx.x; e < n; e += gridDim.x*blockDim.x)
    atomicAdd(&cnt[dst[e]], 1);
}

__global__ __launch_bounds__(1024) void k_scan1(const int* __restrict__ cnt, int n,
                                                int* __restrict__ offs, int* __restrict__ part){
  __shared__ int sh[1024];
  int tid = threadIdx.x;
  int i = blockIdx.x*1024 + tid;
  int v = (i < n) ? cnt[i] : 0;
  sh[tid] = v;
  __syncthreads();
  for (int d = 1; d < 1024; d <<= 1){
    int t = (tid >= d) ? sh[tid-d] : 0;
    __syncthreads();
    sh[tid] += t;
    __syncthreads();
  }
  if (i < n) offs[i] = sh[tid] - v;
  if (tid == 1023) part[blockIdx.x] = sh[1023];
}

__global__ void k_scan2(int* part, int nb){
  __shared__ int sh[128];
  int tid = threadIdx.x;
  int v = (tid < nb) ? part[tid] : 0;
  sh[tid] = v;
  __syncthreads();
  for (int d = 1; d < 128; d <<= 1){
    int t = (tid >= d) ? sh[tid-d] : 0;
    __syncthreads();
    sh[tid] += t;
    __syncthreads();
  }
  if (tid < nb) part[tid] = sh[tid] - v;
}

__global__ __launch_bounds__(1024) void k_scan3(int* offs, int n, const int* __restrict__ part, int total){
  int i = blockIdx.x*1024 + threadIdx.x;
  if (i < n) offs[i] += part[blockIdx.x];
  if (i == 0) offs[n] = total;
}

__global__ void k_fill2(const int* __restrict__ src, const int* __restrict__ dst,
                        const float* __restrict__ w, int n, const int* __restrict__ offs,
                        int* __restrict__ cur, int4* __restrict__ ed){
  for (int e = blockIdx.x*blockDim.x + threadIdx.x; e < n; e += gridDim.x*blockDim.x){
    int d = dst[e];
    int p = offs[d] + atomicAdd(&cur[d], 1);
    ed[p] = make_int4(src[e], __float_as_int(w[e]), d, 0);
  }
}

// ----------------- weight prep: f16 transposed copies -----------------
// wt_in[n][k] (128x384); wcat{0,1}[n][k] (128x256) = [W_rel[l,1]; W_root[l,1]]^T
__global__ __launch_bounds__(256) void k_prep(const float* __restrict__ W_in,
                                              const float* __restrict__ W_rel,
                                              const float* __restrict__ W_root,
                                              _Float16* __restrict__ wt_in,
                                              _Float16* __restrict__ wcat0,
                                              _Float16* __restrict__ wcat1){
  int i = blockIdx.x*256 + threadIdx.x;
  if (i < 49152){
    int n = i / 384, k = i % 384;
    wt_in[i] = (_Float16)W_in[k*128 + n];
  } else if (i < 49152 + 32768){
    int j = i - 49152;
    int n = j / 256, k = j % 256;
    const float* Wr = W_rel  + 1*16384;
    const float* Wo = W_root + 1*16384;
    wcat0[j] = (_Float16)(k < 128 ? Wr[k*128+n] : Wo[(k-128)*128+n]);
  } else if (i < 49152 + 65536){
    int j = i - 49152 - 32768;
    int n = j / 256, k = j % 256;
    const float* Wr = W_rel  + 3*16384;
    const float* Wo = W_root + 3*16384;
    wcat1[j] = (_Float16)(k < 128 ? Wr[k*128+n] : Wo[(k-128)*128+n]);
  }
}

// ----------------- edge gate MLP -----------------
__global__ void k_gate(const float* __restrict__ ea,
                       const float* __restrict__ eW1, const float* __restrict__ eb1,
                       const float* __restrict__ eW2, const float* __restrict__ eb2,
                       const float* __restrict__ eW3, const float* __restrict__ eb3,
                       float* __restrict__ wout, int n){
  __shared__ float w1[11*32], b1[32], w2[32*16], b2[16], w3[16];
  __shared__ float b3;
  int tid = threadIdx.x;
  for (int i = tid; i < 11*32; i += blockDim.x) w1[i] = eW1[i];
  for (int i = tid; i < 32;    i += blockDim.x) b1[i] = eb1[i];
  for (int i = tid; i < 32*16; i += blockDim.x) w2[i] = eW2[i];
  for (int i = tid; i < 16;    i += blockDim.x) b2[i] = eb2[i];
  for (int i = tid; i < 16;    i += blockDim.x) w3[i] = eW3[i];
  if (tid == 0) b3 = eb3[0];
  __syncthreads();
  for (int e = blockIdx.x*blockDim.x + tid; e < n; e += gridDim.x*blockDim.x){
    float sent  = fminf(fmaxf(ea[2*e], -1.f), 1.f);
    float decay = ea[2*e+1];
    float dt = fmaxf(-logf(fmaxf(decay, 1e-6f)) * 100.f, 0.f);
    float ds = fminf(dt * (1.f/30.f), 12.f);
    float x[11];
    x[0] = sent; x[1] = log1pf(dt);
    x[2] = sinf(ds);     x[3] = sinf(2.f*ds); x[4] = sinf(3.f*ds); x[5] = sinf(4.f*ds);
    x[6] = cosf(ds);     x[7] = cosf(2.f*ds); x[8] = cosf(3.f*ds); x[9] = cosf(4.f*ds);
    x[10] = ds;
    float h1[32];
    #pragma unroll
    for (int j = 0; j < 32; j++){
      float s = b1[j];
      #pragma unroll
      for (int i = 0; i < 11; i++) s += x[i]*w1[i*32+j];
      h1[j] = fmaxf(s, 0.f);
    }
    float o = b3;
    #pragma unroll
    for (int j = 0; j < 16; j++){
      float s = b2[j];
      #pragma unroll
      for (int i = 0; i < 32; i++) s += h1[i]*w2[i*16+j];
      o += fmaxf(s, 0.f)*w3[j];
    }
    wout[e] = 1.f/(1.f + expf(-o));
  }
}

// ----------------- simple input projection (comp side, small) -----------------
template<int K, int R>
__global__ __launch_bounds__(128) void k_input_s(const float* __restrict__ X, const float* __restrict__ W,
                                                 const float* __restrict__ bias, float* __restrict__ Y){
  __shared__ float xs[R*K];
  int t = threadIdx.x;
  long row0 = (long)blockIdx.x * R;
  const float4* src = (const float4*)(X + row0*K);
  float4* d4 = (float4*)xs;
  for (int i = t; i < R*K/4; i += 128) d4[i] = src[i];
  __syncthreads();
  float acc[R];
  #pragma unroll
  for (int r = 0; r < R; r++) acc[r] = 0.f;
  for (int k4 = 0; k4 < K/4; k4++){
    int kb = k4*4;
    float w0 = W[(kb+0)*H+t], w1 = W[(kb+1)*H+t], w2 = W[(kb+2)*H+t], w3 = W[(kb+3)*H+t];
    #pragma unroll
    for (int r = 0; r < R; r++){
      float4 xv = ((const float4*)(xs + r*K))[k4];
      acc[r] += xv.x*w0 + xv.y*w1 + xv.z*w2 + xv.w*w3;
    }
  }
  float b = bias[t];
  #pragma unroll
  for (int r = 0; r < R; r++)
    Y[(row0+r)*H + t] = fmaxf(acc[r] + b, 0.f);
}

// ----------------- MFMA input projection (fact side): 16 rows / 64-thread block
// A: X rows staged f16 in LDS (wave-local, no barriers). B: Wt[n][k] f16 from L2.
// 12 K-steps x 8 n-tiles of mfma_f32_16x16x32_f16.
__global__ __launch_bounds__(64) void k_input_m(const float* __restrict__ X,
                                                const _Float16* __restrict__ Wt,
                                                const float* __restrict__ bias,
                                                float* __restrict__ Y){
  __shared__ _Float16 xs[16][392];   // 384 + 8 pad (bank decorrelation)
  int t = threadIdx.x;
  int m = t & 15, q = t >> 4;
  long row0 = (long)blockIdx.x * 16;
  #pragma unroll 4
  for (int r = 0; r < 16; r++){
    const float4* src = (const float4*)(X + (row0 + r)*384);
    ((short4*)xs[r])[t] = f4_to_h4(src[t]);
    if (t < 32) ((short4*)xs[r])[64+t] = f4_to_h4(src[64+t]);
  }
  floatx4 acc[8];
  #pragma unroll
  for (int nt = 0; nt < 8; nt++) acc[nt] = (floatx4){0.f,0.f,0.f,0.f};
  #pragma unroll 4
  for (int ks = 0; ks < 12; ks++){
    half8_t av = *(const half8_t*)&xs[m][ks*32 + q*8];
    #pragma unroll
    for (int nt = 0; nt < 8; nt++){
      half8_t bv = *(const half8_t*)(Wt + (size_t)(nt*16 + m)*384 + ks*32 + q*8);
      acc[nt] = __builtin_amdgcn_mfma_f32_16x16x32_f16(av, bv, acc[nt], 0, 0, 0);
    }
  }
  #pragma unroll
  for (int nt = 0; nt < 8; nt++){
    int col = nt*16 + m;
    float b = bias[col];
    #pragma unroll
    for (int i = 0; i < 4; i++)
      Y[(row0 + q*4 + i)*H + col] = fmaxf(acc[nt][i] + b, 0.f);
  }
}

// ----------------- MFMA fused fact layer: 16 rows / 64-thread block ---------
// fp32 gather (2 groups x 32 lanes, 8 rows each) flushed to f16 LDS;
// MFMA K=256 over [agg|prev] x Wcat_t; relu+residual+LN epilogue in C-layout.
__global__ __launch_bounds__(64) void k_layer_m(
    const float* __restrict__ xsrc, const float* __restrict__ xprev,
    const int* __restrict__ offs, const int4* __restrict__ ed,
    const _Float16* __restrict__ Wt, const float* __restrict__ brel,
    const float* __restrict__ lnsc, const float* __restrict__ lnbi,
    float* __restrict__ xnext){
  __shared__ _Float16 xin[16][264];  // [row][ agg 0..127 | prev 128..255 ] + 8 pad
  int t = threadIdx.x, c = t & 31, g = t >> 5;
  long row0 = (long)blockIdx.x * 16;
  int grow0 = g*8;
  #pragma unroll
  for (int j = 0; j < 8; j++){
    int lr = grow0 + j;
    ((short4*)&xin[lr][0])[c] = make_short4(0,0,0,0);
    float4 pv = ((const float4*)(xprev + (row0+lr)*H))[c];
    ((short4*)&xin[lr][128])[c] = f4_to_h4(pv);
  }
  // gather (fp32 accumulate, flush-on-row-change to f16 LDS)
  int lo = offs[row0 + grow0], hi = offs[row0 + grow0 + 8];
  float4 a = make_float4(0.f,0.f,0.f,0.f);
  int cur = (int)row0 + grow0;
  int idx = lo;
  for (; idx + 8 <= hi; idx += 8){
    int4 mrec[8];
    #pragma unroll
    for (int j = 0; j < 8; j++) mrec[j] = ed[idx+j];
    float4 v[8];
    #pragma unroll
    for (int j = 0; j < 8; j++) v[j] = ((const float4*)(xsrc + (long)mrec[j].x*H))[c];
    #pragma unroll
    for (int j = 0; j < 8; j++){
      float w = __int_as_float(mrec[j].y);
      if (mrec[j].z != cur){ ((short4*)&xin[cur-(int)row0][0])[c] = f4_to_h4(a); a = make_float4(0.f,0.f,0.f,0.f); cur = mrec[j].z; }
      a.x += v[j].x*w; a.y += v[j].y*w; a.z += v[j].z*w; a.w += v[j].w*w;
    }
  }
  for (; idx < hi; idx++){
    int4 mrec = ed[idx];
    float4 v = ((const float4*)(xsrc + (long)mrec.x*H))[c];
    float w = __int_as_float(mrec.y);
    if (mrec.z != cur){ ((short4*)&xin[cur-(int)row0][0])[c] = f4_to_h4(a); a = make_float4(0.f,0.f,0.f,0.f); cur = mrec.z; }
    a.x += v.x*w; a.y += v.y*w; a.z += v.z*w; a.w += v.w*w;
  }
  if (lo < hi) ((short4*)&xin[cur-(int)row0][0])[c] = f4_to_h4(a);

  // MFMA: 8 K-steps x 8 n-tiles
  int m = t & 15, q = t >> 4;
  floatx4 acc[8];
  #pragma unroll
  for (int nt = 0; nt < 8; nt++) acc[nt] = (floatx4){0.f,0.f,0.f,0.f};
  #pragma unroll
  for (int ks = 0; ks < 8; ks++){
    half8_t av = *(const half8_t*)&xin[m][ks*32 + q*8];
    #pragma unroll
    for (int nt = 0; nt < 8; nt++){
      half8_t bv = *(const half8_t*)(Wt + (size_t)(nt*16 + m)*256 + ks*32 + q*8);
      acc[nt] = __builtin_amdgcn_mfma_f32_16x16x32_f16(av, bv, acc[nt], 0, 0, 0);
    }
  }
  // epilogue: bias + relu + residual + LN (rows q*4+i live on lanes 16q..16q+15)
  float vs[8][4];
  float s[4] = {0.f,0.f,0.f,0.f}, ss[4] = {0.f,0.f,0.f,0.f};
  #pragma unroll
  for (int nt = 0; nt < 8; nt++){
    int col = nt*16 + m;
    float b = brel[col];
    #pragma unroll
    for (int i = 0; i < 4; i++){
      int lr = q*4 + i;
      float pv = (float)xin[lr][128 + col];
      float v = fmaxf(acc[nt][i] + b, 0.f) + pv;
      vs[nt][i] = v;
      s[i] += v; ss[i] += v*v;
    }
  }
  #pragma unroll
  for (int i = 0; i < 4; i++){
    #pragma unroll
    for (int mm = 1; mm < 16; mm <<= 1){
      s[i]  += __shfl_xor(s[i],  mm, 64);
      ss[i] += __shfl_xor(ss[i], mm, 64);
    }
  }
  #pragma unroll
  for (int nt = 0; nt < 8; nt++){
    int col = nt*16 + m;
    float lsc = lnsc[col], lbi = lnbi[col];
    #pragma unroll
    for (int i = 0; i < 4; i++){
      float mu  = s[i]*(1.f/H);
      float var = ss[i]*(1.f/H) - mu*mu;
      float rstd = rsqrtf(var + 1e-5f);
      xnext[(row0 + q*4 + i)*H + col] = (vs[nt][i] - mu)*rstd*lsc + lbi;
    }
  }
}

// ----------------- fp32 fused layer (comp side), proven R4 config -----------
template<int R>
__global__ __launch_bounds__(128) void k_layer(
    const float* __restrict__ xsrc, const float* __restrict__ xprev,
    const int* __restrict__ offs, const int4* __restrict__ ed,
    const float* __restrict__ Wrel, const float* __restrict__ brel,
    const float* __restrict__ Wroot, const float* __restrict__ lnsc,
    const float* __restrict__ lnbi, float* __restrict__ xnext){
  constexpr int RG = R/4;
  __shared__ float xin[R][256];
  int t = threadIdx.x, c = t & 31, g = t >> 5;
  long row0 = (long)blockIdx.x * R;
  int grow0 = g*RG;
  #pragma unroll
  for (int j = 0; j < RG; j++){
    int lr = grow0 + j;
    ((float4*)&xin[lr][0])[c] = make_float4(0.f,0.f,0.f,0.f);
    ((float4*)&xin[lr][128])[c] = ((const float4*)(xprev + (row0+lr)*H))[c];
  }
  int lo = offs[row0 + grow0], hi = offs[row0 + grow0 + RG];
  float4 a = make_float4(0.f,0.f,0.f,0.f);
  int cur = (int)row0 + grow0;
  int idx = lo;
  for (; idx + 8 <= hi; idx += 8){
    int4 m[8];
    #pragma unroll
    for (int j = 0; j < 8; j++) m[j] = ed[idx+j];
    float4 v[8];
    #pragma unroll
    for (int j = 0; j < 8; j++) v[j] = ((const float4*)(xsrc + (long)m[j].x*H))[c];
    #pragma unroll
    for (int j = 0; j < 8; j++){
      float w = __int_as_float(m[j].y);
      if (m[j].z != cur){ ((float4*)&xin[cur-(int)row0][0])[c] = a; a = make_float4(0.f,0.f,0.f,0.f); cur = m[j].z; }
      a.x += v[j].x*w; a.y += v[j].y*w; a.z += v[j].z*w; a.w += v[j].w*w;
    }
  }
  for (; idx < hi; idx++){
    int4 m = ed[idx];
    float4 v = ((const float4*)(xsrc + (long)m.x*H))[c];
    float w = __int_as_float(m.y);
    if (m.z != cur){ ((float4*)&xin[cur-(int)row0][0])[c] = a; a = make_float4(0.f,0.f,0.f,0.f); cur = m.z; }
    a.x += v.x*w; a.y += v.y*w; a.z += v.z*w; a.w += v.w*w;
  }
  if (lo < hi) ((float4*)&xin[cur-(int)row0][0])[c] = a;

  float4 acc[RG];
  float4 bv = ((const float4*)brel)[c];
  #pragma unroll
  for (int j = 0; j < RG; j++) acc[j] = bv;
  #pragma unroll
  for (int p = 0; p < 2; p++){
    const float4* Wp = (const float4*)(p ? Wroot : Wrel) + c;
    #pragma unroll 4
    for (int k4 = 0; k4 < 32; k4++){
      float4 xv[RG];
      #pragma unroll
      for (int j = 0; j < RG; j++)
        xv[j] = ((const float4*)xin[grow0+j])[p*32 + k4];
      #pragma unroll
      for (int kk = 0; kk < 4; kk++){
        float4 wv = Wp[(size_t)(k4*4+kk)*32];
        #pragma unroll
        for (int j = 0; j < RG; j++){
          float xk = (kk==0) ? xv[j].x : (kk==1) ? xv[j].y : (kk==2) ? xv[j].z : xv[j].w;
          acc[j].x += xk*wv.x; acc[j].y += xk*wv.y; acc[j].z += xk*wv.z; acc[j].w += xk*wv.w;
        }
      }
    }
  }
  float4 lsc = ((const float4*)lnsc)[c];
  float4 lbi = ((const float4*)lnbi)[c];
  #pragma unroll
  for (int j = 0; j < RG; j++){
    int lr = grow0 + j;
    float4 pv = ((const float4*)&xin[lr][128])[c];
    float4 v;
    v.x = fmaxf(acc[j].x, 0.f) + pv.x;
    v.y = fmaxf(acc[j].y, 0.f) + pv.y;
    v.z = fmaxf(acc[j].z, 0.f) + pv.z;
    v.w = fmaxf(acc[j].w, 0.f) + pv.w;
    float s  = v.x + v.y + v.z + v.w;
    float ss = v.x*v.x + v.y*v.y + v.z*v.z + v.w*v.w;
    #pragma unroll
    for (int mm = 1; mm < 32; mm <<= 1){ s += __shfl_xor(s, mm, 64); ss += __shfl_xor(ss, mm, 64); }
    float mu  = s*(1.f/H);
    float var = ss*(1.f/H) - mu*mu;
    float rstd = rsqrtf(var + 1e-5f);
    float4 o;
    o.x = (v.x - mu)*rstd*lsc.x + lbi.x;
    o.y = (v.y - mu)*rstd*lsc.y + lbi.y;
    o.z = (v.z - mu)*rstd*lsc.z + lbi.z;
    o.w = (v.w - mu)*rstd*lsc.w + lbi.w;
    ((float4*)(xnext + (row0+lr)*H))[c] = o;
  }
}

// ----------------- pooling -----------------
#define PCHUNK 128
#define FBLK ((NFACT + PCHUNK - 1) / PCHUNK)
#define CBLK ((NCOMP + PCHUNK - 1) / PCHUNK)

__global__ __launch_bounds__(128) void k_pool_acc(const float* __restrict__ xf, const float* __restrict__ xc,
                                                  const int* __restrict__ fb, const int* __restrict__ cb,
                                                  float* __restrict__ pooled){
  int t = threadIdx.x;
  int b = blockIdx.x;
  if (b < FBLK){
    int start = b*PCHUNK, end = start + PCHUNK; if (end > NFACT) end = NFACT;
    float s = 0.f; int curb = -1;
    for (int i = start; i < end; i++){
      int bb = fb[i];
      if (bb != curb){
        if (curb >= 0) atomicAdd(&pooled[curb*256 + t], s);
        curb = bb; s = 0.f;
      }
      s += xf[(long)i*H + t];
    }
    if (curb >= 0) atomicAdd(&pooled[curb*256 + t], s);
  } else {
    int bbk = b - FBLK;
    int start = bbk*PCHUNK, end = start + PCHUNK; if (end > NCOMP) end = NCOMP;
    float s = 0.f; int curb = -1;
    for (int i = start; i < end; i++){
      int bb = cb[i];
      if (bb != curb){
        if (curb >= 0) atomicAdd(&pooled[curb*256 + 128 + t], s);
        curb = bb; s = 0.f;
      }
      s += xc[(long)i*H + t];
    }
    if (curb >= 0) atomicAdd(&pooled[curb*256 + 128 + t], s);
  }
}

// ----------------- classifier head -----------------
__device__ inline int lowerb(const int* a, int n, int key){
  int lo = 0, hi = n;
  while (lo < hi){ int m = (lo+hi) >> 1; if (a[m] < key) lo = m+1; else hi = m; }
  return lo;
}

__global__ __launch_bounds__(128) void k_head(const float* __restrict__ pooled,
                                              const int* __restrict__ fb, const int* __restrict__ cb,
                                              const float* __restrict__ Wc1, const float* __restrict__ bc1,
                                              const float* __restrict__ Wc2, const float* __restrict__ bc2,
                                              float* __restrict__ out){
  __shared__ float p[256];
  __shared__ float red[2];
  int t = threadIdx.x, b = blockIdx.x;
  int flo = lowerb(fb, NFACT, b), fhi = lowerb(fb, NFACT, b+1);
  int clo = lowerb(cb, NCOMP, b), chi = lowerb(cb, NCOMP, b+1);
  float fc = (float)((fhi - flo) > 1 ? (fhi - flo) : 1);
  float cc = (float)((chi - clo) > 1 ? (chi - clo) : 1);
  p[t]       = pooled[b*256 + t] / fc;
  p[128 + t] = pooled[b*256 + 128 + t] / cc;
  __syncthreads();
  float acc = bc1[t];
  #pragma unroll 4
  for (int k = 0; k < 256; k++) acc += p[k]*Wc1[k*H + t];
  float h = fmaxf(acc, 0.f)*Wc2[t];
  #pragma unroll
  for (int m = 1; m < 64; m <<= 1) h += __shfl_xor(h, m, 64);
  if ((t & 63) == 0) red[t>>6] = h;
  __syncthreads();
  if (t == 0) out[b] = red[0] + red[1] + bc2[0];
}

extern "C" void kernel_launch(void* const* d_in, const int* in_sizes, int n_in,
                              void* d_out, int out_size, void* d_ws, size_t ws_size,
                              hipStream_t stream){
  const float* x_fact = (const float*)d_in[0];
  const float* x_comp = (const float*)d_in[1];
  const float* ea_f2c = (const float*)d_in[2];
  const float* ea_c2f = (const float*)d_in[3];
  const int* s_f2c   = (const int*)d_in[4];
  const int* dst_f2c = (const int*)d_in[5];
  const int* s_c2f   = (const int*)d_in[6];
  const int* dst_c2f = (const int*)d_in[7];
  const int* fb = (const int*)d_in[8];
  const int* cb = (const int*)d_in[9];
  const float* W_in_f = (const float*)d_in[10];
  const float* b_in_f = (const float*)d_in[11];
  const float* W_in_c = (const float*)d_in[12];
  const float* b_in_c = (const float*)d_in[13];
  const float* eW1 = (const float*)d_in[14]; const float* eb1 = (const float*)d_in[15];
  const float* eW2 = (const float*)d_in[16]; const float* eb2 = (const float*)d_in[17];
  const float* eW3 = (const float*)d_in[18]; const float* eb3 = (const float*)d_in[19];
  const float* W_rel = (const float*)d_in[20]; const float* b_rel = (const float*)d_in[21];
  const float* W_root = (const float*)d_in[22];
  const float* ln_s = (const float*)d_in[23]; const float* ln_b = (const float*)d_in[24];
  const float* Wc1 = (const float*)d_in[25]; const float* bc1 = (const float*)d_in[26];
  const float* Wc2 = (const float*)d_in[27]; const float* bc2 = (const float*)d_in[28];
  float* out = (float*)d_out;

  char* ws = (char*)d_ws;
  size_t off = 0;
  auto alloc = [&](size_t bytes)->char*{ char* p = ws + off; off = (off + bytes + 255) & ~(size_t)255; return p; };
  float* xf0   = (float*)alloc((size_t)NFACT*H*4);
  float* xf1   = (float*)alloc((size_t)NFACT*H*4);
  float* xc0   = (float*)alloc((size_t)NCOMP*H*4);
  float* xc1   = (float*)alloc((size_t)NCOMP*H*4);
  float* w_f2c = (float*)alloc((size_t)EDGES*4);
  float* w_c2f = (float*)alloc((size_t)EDGES*4);
  int4* ed_f2c = (int4*)alloc((size_t)EDGES*16);
  int4* ed_c2f = (int4*)alloc((size_t)EDGES*16);
  int* off_f2c = (int*)alloc((size_t)(NCOMP+1)*4);
  int* cur_f2c = (int*)alloc((size_t)NCOMP*4);
  int* off_c2f = (int*)alloc((size_t)(NFACT+1)*4);
  int* cur_c2f = (int*)alloc((size_t)NFACT*4);
  int* part    = (int*)alloc(128*4);
  float* pooled= (float*)alloc((size_t)BATCH*256*4);
  _Float16* wt_in = (_Float16*)alloc((size_t)49152*2);
  _Float16* wcat0 = (_Float16*)alloc((size_t)32768*2);
  _Float16* wcat1 = (_Float16*)alloc((size_t)32768*2);

  // --- weight prep (f16 transposed) + edge gates ---
  k_prep<<<448,256,0,stream>>>(W_in_f, W_rel, W_root, wt_in, wcat0, wcat1);
  k_gate<<<512,256,0,stream>>>(ea_f2c, eW1,eb1,eW2,eb2,eW3,eb3, w_f2c, EDGES);
  k_gate<<<512,256,0,stream>>>(ea_c2f, eW1,eb1,eW2,eb2,eW3,eb3, w_c2f, EDGES);

  // --- CSR f2c (dst in comp space) ---
  hipMemsetAsync(cur_f2c, 0, NCOMP*4, stream);
  k_hist<<<512,256,0,stream>>>(dst_f2c, EDGES, cur_f2c);
  {
    int nb = (NCOMP + 1023)/1024;
    k_scan1<<<nb,1024,0,stream>>>(cur_f2c, NCOMP, off_f2c, part);
    k_scan2<<<1,128,0,stream>>>(part, nb);
    k_scan3<<<nb,1024,0,stream>>>(off_f2c, NCOMP, part, EDGES);
  }
  hipMemsetAsync(cur_f2c, 0, NCOMP*4, stream);
  k_fill2<<<512,256,0,stream>>>(s_f2c, dst_f2c, w_f2c, EDGES, off_f2c, cur_f2c, ed_f2c);

  // --- CSR c2f (dst in fact space) ---
  hipMemsetAsync(cur_c2f, 0, NFACT*4, stream);
  k_hist<<<512,256,0,stream>>>(dst_c2f, EDGES, cur_c2f);
  {
    int nb = (NFACT + 1023)/1024;
    k_scan1<<<nb,1024,0,stream>>>(cur_c2f, NFACT, off_c2f, part);
    k_scan2<<<1,128,0,stream>>>(part, nb);
    k_scan3<<<nb,1024,0,stream>>>(off_c2f, NFACT, part, EDGES);
  }
  hipMemsetAsync(cur_c2f, 0, NFACT*4, stream);
  k_fill2<<<512,256,0,stream>>>(s_c2f, dst_c2f, w_c2f, EDGES, off_c2f, cur_c2f, ed_c2f);

  // --- input projections ---
  k_input_m<<<NFACT/16,64,0,stream>>>(x_fact, wt_in, b_in_f, xf0);
  k_input_s<64,8><<<NCOMP/8,128,0,stream>>>(x_comp, W_in_c, b_in_c, xc0);

  // --- GNN layers ---
  const float* xf_p = xf0; const float* xc_p = xc0;
  float* xf_n = xf1; float* xc_n = xc1;
  for (int l = 0; l < 2; l++){
    const float* Wr0 = W_rel  + (size_t)(l*2+0)*H*H;
    const float* br0 = b_rel  + (size_t)(l*2+0)*H;
    const float* br1 = b_rel  + (size_t)(l*2+1)*H;
    const float* Wo0 = W_root + (size_t)(l*2+0)*H*H;
    const _Float16* wcat = (l == 0) ? wcat0 : wcat1;
    k_layer<4><<<NCOMP/4,128,0,stream>>>(xf_p, xc_p, off_f2c, ed_f2c,
                                         Wr0, br0, Wo0, ln_s + H, ln_b + H, xc_n);
    k_layer_m<<<NFACT/16,64,0,stream>>>(xc_p, xf_p, off_c2f, ed_c2f,
                                        wcat, br1, ln_s, ln_b, xf_n);
    const float* tf = xf_p; xf_p = xf_n; xf_n = (float*)tf;
    const float* tc = xc_p; xc_p = xc_n; xc_n = (float*)tc;
  }

  // --- pooling + head ---
  hipMemsetAsync(pooled, 0, (size_t)BATCH*256*4, stream);
  k_pool_acc<<<FBLK + CBLK,128,0,stream>>>(xf_p, xc_p, fb, cb, pooled);
  k_head<<<BATCH,128,0,stream>>>(pooled, fb, cb, Wc1, bc1, Wc2, bc2, out);
}

// Round 7
// 1066.236 us; speedup vs baseline: 1.4589x; 1.0226x over previous
//
#include <hip/hip_runtime.h>
#include <math.h>

#define H 128
#define EDGES 500000
#define NFACT 100000
#define NCOMP 5000
#define BATCH 64

typedef _Float16 half8_t __attribute__((ext_vector_type(8)));
typedef float floatx4 __attribute__((ext_vector_type(4)));

__device__ inline short4 f4_to_h4(float4 v){
  union { short4 s; _Float16 h[4]; } u;
  u.h[0]=(_Float16)v.x; u.h[1]=(_Float16)v.y; u.h[2]=(_Float16)v.z; u.h[3]=(_Float16)v.w;
  return u.s;
}

__device__ inline half8_t f8_to_h8(float4 a, float4 b){
  half8_t r;
  r[0]=(_Float16)a.x; r[1]=(_Float16)a.y; r[2]=(_Float16)a.z; r[3]=(_Float16)a.w;
  r[4]=(_Float16)b.x; r[5]=(_Float16)b.y; r[6]=(_Float16)b.z; r[7]=(_Float16)b.w;
  return r;
}

// ----------------- CSR build -----------------
__global__ void k_hist(const int* __restrict__ dst, int n, int* __restrict__ cnt){
  for (int e = blockIdx.x*blockDim.x + threadIdx.x; e < n; e += gridDim.x*blockDim.x)
    atomicAdd(&cnt[dst[e]], 1);
}

__global__ __launch_bounds__(1024) void k_scan1(const int* __restrict__ cnt, int n,
                                                int* __restrict__ offs, int* __restrict__ part){
  __shared__ int sh[1024];
  int tid = threadIdx.x;
  int i = blockIdx.x*1024 + tid;
  int v = (i < n) ? cnt[i] : 0;
  sh[tid] = v;
  __syncthreads();
  for (int d = 1; d < 1024; d <<= 1){
    int t = (tid >= d) ? sh[tid-d] : 0;
    __syncthreads();
    sh[tid] += t;
    __syncthreads();
  }
  if (i < n) offs[i] = sh[tid] - v;
  if (tid == 1023) part[blockIdx.x] = sh[1023];
}

__global__ void k_scan2(int* part, int nb){
  __shared__ int sh[128];
  int tid = threadIdx.x;
  int v = (tid < nb) ? part[tid] : 0;
  sh[tid] = v;
  __syncthreads();
  for (int d = 1; d < 128; d <<= 1){
    int t = (tid >= d) ? sh[tid-d] : 0;
    __syncthreads();
    sh[tid] += t;
    __syncthreads();
  }
  if (tid < nb) part[tid] = sh[tid] - v;
}

__global__ __launch_bounds__(1024) void k_scan3(int* offs, int n, const int* __restrict__ part, int total){
  int i = blockIdx.x*1024 + threadIdx.x;
  if (i < n) offs[i] += part[blockIdx.x];
  if (i == 0) offs[n] = total;
}

__global__ void k_fill2(const int* __restrict__ src, const int* __restrict__ dst,
                        const float* __restrict__ w, int n, const int* __restrict__ offs,
                        int* __restrict__ cur, int4* __restrict__ ed){
  for (int e = blockIdx.x*blockDim.x + threadIdx.x; e < n; e += gridDim.x*blockDim.x){
    int d = dst[e];
    int p = offs[d] + atomicAdd(&cur[d], 1);
    ed[p] = make_int4(src[e], __float_as_int(w[e]), d, 0);
  }
}

// ----------------- weight prep: f16 transposed copies -----------------
__global__ __launch_bounds__(256) void k_prep(const float* __restrict__ W_in,
                                              const float* __restrict__ W_rel,
                                              const float* __restrict__ W_root,
                                              _Float16* __restrict__ wt_in,
                                              _Float16* __restrict__ wcat0,
                                              _Float16* __restrict__ wcat1){
  int i = blockIdx.x*256 + threadIdx.x;
  if (i < 49152){
    int n = i / 384, k = i % 384;
    wt_in[i] = (_Float16)W_in[k*128 + n];
  } else if (i < 49152 + 32768){
    int j = i - 49152;
    int n = j / 256, k = j % 256;
    const float* Wr = W_rel  + 1*16384;
    const float* Wo = W_root + 1*16384;
    wcat0[j] = (_Float16)(k < 128 ? Wr[k*128+n] : Wo[(k-128)*128+n]);
  } else if (i < 49152 + 65536){
    int j = i - 49152 - 32768;
    int n = j / 256, k = j % 256;
    const float* Wr = W_rel  + 3*16384;
    const float* Wo = W_root + 3*16384;
    wcat1[j] = (_Float16)(k < 128 ? Wr[k*128+n] : Wo[(k-128)*128+n]);
  }
}

// ----------------- edge gate MLP -----------------
__global__ void k_gate(const float* __restrict__ ea,
                       const float* __restrict__ eW1, const float* __restrict__ eb1,
                       const float* __restrict__ eW2, const float* __restrict__ eb2,
                       const float* __restrict__ eW3, const float* __restrict__ eb3,
                       float* __restrict__ wout, int n){
  __shared__ float w1[11*32], b1[32], w2[32*16], b2[16], w3[16];
  __shared__ float b3;
  int tid = threadIdx.x;
  for (int i = tid; i < 11*32; i += blockDim.x) w1[i] = eW1[i];
  for (int i = tid; i < 32;    i += blockDim.x) b1[i] = eb1[i];
  for (int i = tid; i < 32*16; i += blockDim.x) w2[i] = eW2[i];
  for (int i = tid; i < 16;    i += blockDim.x) b2[i] = eb2[i];
  for (int i = tid; i < 16;    i += blockDim.x) w3[i] = eW3[i];
  if (tid == 0) b3 = eb3[0];
  __syncthreads();
  for (int e = blockIdx.x*blockDim.x + tid; e < n; e += gridDim.x*blockDim.x){
    float sent  = fminf(fmaxf(ea[2*e], -1.f), 1.f);
    float decay = ea[2*e+1];
    float dt = fmaxf(-logf(fmaxf(decay, 1e-6f)) * 100.f, 0.f);
    float ds = fminf(dt * (1.f/30.f), 12.f);
    float x[11];
    x[0] = sent; x[1] = log1pf(dt);
    x[2] = sinf(ds);     x[3] = sinf(2.f*ds); x[4] = sinf(3.f*ds); x[5] = sinf(4.f*ds);
    x[6] = cosf(ds);     x[7] = cosf(2.f*ds); x[8] = cosf(3.f*ds); x[9] = cosf(4.f*ds);
    x[10] = ds;
    float h1[32];
    #pragma unroll
    for (int j = 0; j < 32; j++){
      float s = b1[j];
      #pragma unroll
      for (int i = 0; i < 11; i++) s += x[i]*w1[i*32+j];
      h1[j] = fmaxf(s, 0.f);
    }
    float o = b3;
    #pragma unroll
    for (int j = 0; j < 16; j++){
      float s = b2[j];
      #pragma unroll
      for (int i = 0; i < 32; i++) s += h1[i]*w2[i*16+j];
      o += fmaxf(s, 0.f)*w3[j];
    }
    wout[e] = 1.f/(1.f + expf(-o));
  }
}

// ----------------- simple input projection (comp side, small) -----------------
template<int K, int R>
__global__ __launch_bounds__(128) void k_input_s(const float* __restrict__ X, const float* __restrict__ W,
                                                 const float* __restrict__ bias, float* __restrict__ Y){
  __shared__ float xs[R*K];
  int t = threadIdx.x;
  long row0 = (long)blockIdx.x * R;
  const float4* src = (const float4*)(X + row0*K);
  float4* d4 = (float4*)xs;
  for (int i = t; i < R*K/4; i += 128) d4[i] = src[i];
  __syncthreads();
  float acc[R];
  #pragma unroll
  for (int r = 0; r < R; r++) acc[r] = 0.f;
  for (int k4 = 0; k4 < K/4; k4++){
    int kb = k4*4;
    float w0 = W[(kb+0)*H+t], w1 = W[(kb+1)*H+t], w2 = W[(kb+2)*H+t], w3 = W[(kb+3)*H+t];
    #pragma unroll
    for (int r = 0; r < R; r++){
      float4 xv = ((const float4*)(xs + r*K))[k4];
      acc[r] += xv.x*w0 + xv.y*w1 + xv.z*w2 + xv.w*w3;
    }
  }
  float b = bias[t];
  #pragma unroll
  for (int r = 0; r < R; r++)
    Y[(row0+r)*H + t] = fmaxf(acc[r] + b, 0.f);
}

// ----------------- MFMA input projection v2: LDS-free -----------------------
// 256-thread blocks = 4 independent waves; each wave does 16 rows.
// A loaded directly from global (lane (m,q) reads X[row0+m][ks*32+q*8..+7],
// 4 lanes/row -> 128 B contiguous segments), converted f32->f16 in-register.
// B from L2-resident Wt[n][k] f16. Fully unrolled 12 K-steps x 8 n-tiles.
__global__ __launch_bounds__(256) void k_input_m(const float* __restrict__ X,
                                                 const _Float16* __restrict__ Wt,
                                                 const float* __restrict__ bias,
                                                 float* __restrict__ Y){
  int lane = threadIdx.x & 63;
  int wv = threadIdx.x >> 6;
  long row0 = ((long)blockIdx.x*4 + wv) * 16;
  if (row0 >= NFACT) return;
  int m = lane & 15, q = lane >> 4;
  const float* xrow = X + (row0 + m)*384 + q*8;
  const _Float16* wb0 = Wt + (size_t)m*384 + q*8;
  floatx4 acc[8];
  #pragma unroll
  for (int nt = 0; nt < 8; nt++) acc[nt] = (floatx4){0.f,0.f,0.f,0.f};
  #pragma unroll
  for (int ks = 0; ks < 12; ks++){
    float4 xa = *(const float4*)(xrow + ks*32);
    float4 xb = *(const float4*)(xrow + ks*32 + 4);
    half8_t av = f8_to_h8(xa, xb);
    #pragma unroll
    for (int nt = 0; nt < 8; nt++){
      half8_t bv = *(const half8_t*)(wb0 + (size_t)nt*16*384 + ks*32);
      acc[nt] = __builtin_amdgcn_mfma_f32_16x16x32_f16(av, bv, acc[nt], 0, 0, 0);
    }
  }
  #pragma unroll
  for (int nt = 0; nt < 8; nt++){
    int col = nt*16 + m;
    float b = bias[col];
    #pragma unroll
    for (int i = 0; i < 4; i++)
      Y[(row0 + q*4 + i)*H + col] = fmaxf(acc[nt][i] + b, 0.f);
  }
}

// ----------------- MFMA fused fact layer: 16 rows / 64-thread block ---------
__global__ __launch_bounds__(64) void k_layer_m(
    const float* __restrict__ xsrc, const float* __restrict__ xprev,
    const int* __restrict__ offs, const int4* __restrict__ ed,
    const _Float16* __restrict__ Wt, const float* __restrict__ brel,
    const float* __restrict__ lnsc, const float* __restrict__ lnbi,
    float* __restrict__ xnext){
  __shared__ _Float16 xin[16][264];  // [row][ agg 0..127 | prev 128..255 ] + 8 pad
  int t = threadIdx.x, c = t & 31, g = t >> 5;
  long row0 = (long)blockIdx.x * 16;
  int grow0 = g*8;
  #pragma unroll
  for (int j = 0; j < 8; j++){
    int lr = grow0 + j;
    ((short4*)&xin[lr][0])[c] = make_short4(0,0,0,0);
    float4 pv = ((const float4*)(xprev + (row0+lr)*H))[c];
    ((short4*)&xin[lr][128])[c] = f4_to_h4(pv);
  }
  int lo = offs[row0 + grow0], hi = offs[row0 + grow0 + 8];
  float4 a = make_float4(0.f,0.f,0.f,0.f);
  int cur = (int)row0 + grow0;
  int idx = lo;
  for (; idx + 8 <= hi; idx += 8){
    int4 mrec[8];
    #pragma unroll
    for (int j = 0; j < 8; j++) mrec[j] = ed[idx+j];
    float4 v[8];
    #pragma unroll
    for (int j = 0; j < 8; j++) v[j] = ((const float4*)(xsrc + (long)mrec[j].x*H))[c];
    #pragma unroll
    for (int j = 0; j < 8; j++){
      float w = __int_as_float(mrec[j].y);
      if (mrec[j].z != cur){ ((short4*)&xin[cur-(int)row0][0])[c] = f4_to_h4(a); a = make_float4(0.f,0.f,0.f,0.f); cur = mrec[j].z; }
      a.x += v[j].x*w; a.y += v[j].y*w; a.z += v[j].z*w; a.w += v[j].w*w;
    }
  }
  for (; idx < hi; idx++){
    int4 mrec = ed[idx];
    float4 v = ((const float4*)(xsrc + (long)mrec.x*H))[c];
    float w = __int_as_float(mrec.y);
    if (mrec.z != cur){ ((short4*)&xin[cur-(int)row0][0])[c] = f4_to_h4(a); a = make_float4(0.f,0.f,0.f,0.f); cur = mrec.z; }
    a.x += v.x*w; a.y += v.y*w; a.z += v.z*w; a.w += v.w*w;
  }
  if (lo < hi) ((short4*)&xin[cur-(int)row0][0])[c] = f4_to_h4(a);

  int m = t & 15, q = t >> 4;
  floatx4 acc[8];
  #pragma unroll
  for (int nt = 0; nt < 8; nt++) acc[nt] = (floatx4){0.f,0.f,0.f,0.f};
  #pragma unroll
  for (int ks = 0; ks < 8; ks++){
    half8_t av = *(const half8_t*)&xin[m][ks*32 + q*8];
    #pragma unroll
    for (int nt = 0; nt < 8; nt++){
      half8_t bv = *(const half8_t*)(Wt + (size_t)(nt*16 + m)*256 + ks*32 + q*8);
      acc[nt] = __builtin_amdgcn_mfma_f32_16x16x32_f16(av, bv, acc[nt], 0, 0, 0);
    }
  }
  float vs[8][4];
  float s[4] = {0.f,0.f,0.f,0.f}, ss[4] = {0.f,0.f,0.f,0.f};
  #pragma unroll
  for (int nt = 0; nt < 8; nt++){
    int col = nt*16 + m;
    float b = brel[col];
    #pragma unroll
    for (int i = 0; i < 4; i++){
      int lr = q*4 + i;
      float pv = (float)xin[lr][128 + col];
      float v = fmaxf(acc[nt][i] + b, 0.f) + pv;
      vs[nt][i] = v;
      s[i] += v; ss[i] += v*v;
    }
  }
  #pragma unroll
  for (int i = 0; i < 4; i++){
    #pragma unroll
    for (int mm = 1; mm < 16; mm <<= 1){
      s[i]  += __shfl_xor(s[i],  mm, 64);
      ss[i] += __shfl_xor(ss[i], mm, 64);
    }
  }
  #pragma unroll
  for (int nt = 0; nt < 8; nt++){
    int col = nt*16 + m;
    float lsc = lnsc[col], lbi = lnbi[col];
    #pragma unroll
    for (int i = 0; i < 4; i++){
      float mu  = s[i]*(1.f/H);
      float var = ss[i]*(1.f/H) - mu*mu;
      float rstd = rsqrtf(var + 1e-5f);
      xnext[(row0 + q*4 + i)*H + col] = (vs[nt][i] - mu)*rstd*lsc + lbi;
    }
  }
}

// ----------------- fp32 fused layer (comp side), proven R4 config -----------
template<int R>
__global__ __launch_bounds__(128) void k_layer(
    const float* __restrict__ xsrc, const float* __restrict__ xprev,
    const int* __restrict__ offs, const int4* __restrict__ ed,
    const float* __restrict__ Wrel, const float* __restrict__ brel,
    const float* __restrict__ Wroot, const float* __restrict__ lnsc,
    const float* __restrict__ lnbi, float* __restrict__ xnext){
  constexpr int RG = R/4;
  __shared__ float xin[R][256];
  int t = threadIdx.x, c = t & 31, g = t >> 5;
  long row0 = (long)blockIdx.x * R;
  int grow0 = g*RG;
  #pragma unroll
  for (int j = 0; j < RG; j++){
    int lr = grow0 + j;
    ((float4*)&xin[lr][0])[c] = make_float4(0.f,0.f,0.f,0.f);
    ((float4*)&xin[lr][128])[c] = ((const float4*)(xprev + (row0+lr)*H))[c];
  }
  int lo = offs[row0 + grow0], hi = offs[row0 + grow0 + RG];
  float4 a = make_float4(0.f,0.f,0.f,0.f);
  int cur = (int)row0 + grow0;
  int idx = lo;
  for (; idx + 8 <= hi; idx += 8){
    int4 m[8];
    #pragma unroll
    for (int j = 0; j < 8; j++) m[j] = ed[idx+j];
    float4 v[8];
    #pragma unroll
    for (int j = 0; j < 8; j++) v[j] = ((const float4*)(xsrc + (long)m[j].x*H))[c];
    #pragma unroll
    for (int j = 0; j < 8; j++){
      float w = __int_as_float(m[j].y);
      if (m[j].z != cur){ ((float4*)&xin[cur-(int)row0][0])[c] = a; a = make_float4(0.f,0.f,0.f,0.f); cur = m[j].z; }
      a.x += v[j].x*w; a.y += v[j].y*w; a.z += v[j].z*w; a.w += v[j].w*w;
    }
  }
  for (; idx < hi; idx++){
    int4 m = ed[idx];
    float4 v = ((const float4*)(xsrc + (long)m.x*H))[c];
    float w = __int_as_float(m.y);
    if (m.z != cur){ ((float4*)&xin[cur-(int)row0][0])[c] = a; a = make_float4(0.f,0.f,0.f,0.f); cur = m.z; }
    a.x += v.x*w; a.y += v.y*w; a.z += v.z*w; a.w += v.w*w;
  }
  if (lo < hi) ((float4*)&xin[cur-(int)row0][0])[c] = a;

  float4 acc[RG];
  float4 bv = ((const float4*)brel)[c];
  #pragma unroll
  for (int j = 0; j < RG; j++) acc[j] = bv;
  #pragma unroll
  for (int p = 0; p < 2; p++){
    const float4* Wp = (const float4*)(p ? Wroot : Wrel) + c;
    #pragma unroll 4
    for (int k4 = 0; k4 < 32; k4++){
      float4 xv[RG];
      #pragma unroll
      for (int j = 0; j < RG; j++)
        xv[j] = ((const float4*)xin[grow0+j])[p*32 + k4];
      #pragma unroll
      for (int kk = 0; kk < 4; kk++){
        float4 wv = Wp[(size_t)(k4*4+kk)*32];
        #pragma unroll
        for (int j = 0; j < RG; j++){
          float xk = (kk==0) ? xv[j].x : (kk==1) ? xv[j].y : (kk==2) ? xv[j].z : xv[j].w;
          acc[j].x += xk*wv.x; acc[j].y += xk*wv.y; acc[j].z += xk*wv.z; acc[j].w += xk*wv.w;
        }
      }
    }
  }
  float4 lsc = ((const float4*)lnsc)[c];
  float4 lbi = ((const float4*)lnbi)[c];
  #pragma unroll
  for (int j = 0; j < RG; j++){
    int lr = grow0 + j;
    float4 pv = ((const float4*)&xin[lr][128])[c];
    float4 v;
    v.x = fmaxf(acc[j].x, 0.f) + pv.x;
    v.y = fmaxf(acc[j].y, 0.f) + pv.y;
    v.z = fmaxf(acc[j].z, 0.f) + pv.z;
    v.w = fmaxf(acc[j].w, 0.f) + pv.w;
    float s  = v.x + v.y + v.z + v.w;
    float ss = v.x*v.x + v.y*v.y + v.z*v.z + v.w*v.w;
    #pragma unroll
    for (int mm = 1; mm < 32; mm <<= 1){ s += __shfl_xor(s, mm, 64); ss += __shfl_xor(ss, mm, 64); }
    float mu  = s*(1.f/H);
    float var = ss*(1.f/H) - mu*mu;
    float rstd = rsqrtf(var + 1e-5f);
    float4 o;
    o.x = (v.x - mu)*rstd*lsc.x + lbi.x;
    o.y = (v.y - mu)*rstd*lsc.y + lbi.y;
    o.z = (v.z - mu)*rstd*lsc.z + lbi.z;
    o.w = (v.w - mu)*rstd*lsc.w + lbi.w;
    ((float4*)(xnext + (row0+lr)*H))[c] = o;
  }
}

// ----------------- pooling -----------------
#define PCHUNK 128
#define FBLK ((NFACT + PCHUNK - 1) / PCHUNK)
#define CBLK ((NCOMP + PCHUNK - 1) / PCHUNK)

__global__ __launch_bounds__(128) void k_pool_acc(const float* __restrict__ xf, const float* __restrict__ xc,
                                                  const int* __restrict__ fb, const int* __restrict__ cb,
                                                  float* __restrict__ pooled){
  int t = threadIdx.x;
  int b = blockIdx.x;
  if (b < FBLK){
    int start = b*PCHUNK, end = start + PCHUNK; if (end > NFACT) end = NFACT;
    float s = 0.f; int curb = -1;
    for (int i = start; i < end; i++){
      int bb = fb[i];
      if (bb != curb){
        if (curb >= 0) atomicAdd(&pooled[curb*256 + t], s);
        curb = bb; s = 0.f;
      }
      s += xf[(long)i*H + t];
    }
    if (curb >= 0) atomicAdd(&pooled[curb*256 + t], s);
  } else {
    int bbk = b - FBLK;
    int start = bbk*PCHUNK, end = start + PCHUNK; if (end > NCOMP) end = NCOMP;
    float s = 0.f; int curb = -1;
    for (int i = start; i < end; i++){
      int bb = cb[i];
      if (bb != curb){
        if (curb >= 0) atomicAdd(&pooled[curb*256 + 128 + t], s);
        curb = bb; s = 0.f;
      }
      s += xc[(long)i*H + t];
    }
    if (curb >= 0) atomicAdd(&pooled[curb*256 + 128 + t], s);
  }
}

// ----------------- classifier head -----------------
__device__ inline int lowerb(const int* a, int n, int key){
  int lo = 0, hi = n;
  while (lo < hi){ int m = (lo+hi) >> 1; if (a[m] < key) lo = m+1; else hi = m; }
  return lo;
}

__global__ __launch_bounds__(128) void k_head(const float* __restrict__ pooled,
                                              const int* __restrict__ fb, const int* __restrict__ cb,
                                              const float* __restrict__ Wc1, const float* __restrict__ bc1,
                                              const float* __restrict__ Wc2, const float* __restrict__ bc2,
                                              float* __restrict__ out){
  __shared__ float p[256];
  __shared__ float red[2];
  int t = threadIdx.x, b = blockIdx.x;
  int flo = lowerb(fb, NFACT, b), fhi = lowerb(fb, NFACT, b+1);
  int clo = lowerb(cb, NCOMP, b), chi = lowerb(cb, NCOMP, b+1);
  float fc = (float)((fhi - flo) > 1 ? (fhi - flo) : 1);
  float cc = (float)((chi - clo) > 1 ? (chi - clo) : 1);
  p[t]       = pooled[b*256 + t] / fc;
  p[128 + t] = pooled[b*256 + 128 + t] / cc;
  __syncthreads();
  float acc = bc1[t];
  #pragma unroll 4
  for (int k = 0; k < 256; k++) acc += p[k]*Wc1[k*H + t];
  float h = fmaxf(acc, 0.f)*Wc2[t];
  #pragma unroll
  for (int m = 1; m < 64; m <<= 1) h += __shfl_xor(h, m, 64);
  if ((t & 63) == 0) red[t>>6] = h;
  __syncthreads();
  if (t == 0) out[b] = red[0] + red[1] + bc2[0];
}

extern "C" void kernel_launch(void* const* d_in, const int* in_sizes, int n_in,
                              void* d_out, int out_size, void* d_ws, size_t ws_size,
                              hipStream_t stream){
  const float* x_fact = (const float*)d_in[0];
  const float* x_comp = (const float*)d_in[1];
  const float* ea_f2c = (const float*)d_in[2];
  const float* ea_c2f = (const float*)d_in[3];
  const int* s_f2c   = (const int*)d_in[4];
  const int* dst_f2c = (const int*)d_in[5];
  const int* s_c2f   = (const int*)d_in[6];
  const int* dst_c2f = (const int*)d_in[7];
  const int* fb = (const int*)d_in[8];
  const int* cb = (const int*)d_in[9];
  const float* W_in_f = (const float*)d_in[10];
  const float* b_in_f = (const float*)d_in[11];
  const float* W_in_c = (const float*)d_in[12];
  const float* b_in_c = (const float*)d_in[13];
  const float* eW1 = (const float*)d_in[14]; const float* eb1 = (const float*)d_in[15];
  const float* eW2 = (const float*)d_in[16]; const float* eb2 = (const float*)d_in[17];
  const float* eW3 = (const float*)d_in[18]; const float* eb3 = (const float*)d_in[19];
  const float* W_rel = (const float*)d_in[20]; const float* b_rel = (const float*)d_in[21];
  const float* W_root = (const float*)d_in[22];
  const float* ln_s = (const float*)d_in[23]; const float* ln_b = (const float*)d_in[24];
  const float* Wc1 = (const float*)d_in[25]; const float* bc1 = (const float*)d_in[26];
  const float* Wc2 = (const float*)d_in[27]; const float* bc2 = (const float*)d_in[28];
  float* out = (float*)d_out;

  char* ws = (char*)d_ws;
  size_t off = 0;
  auto alloc = [&](size_t bytes)->char*{ char* p = ws + off; off = (off + bytes + 255) & ~(size_t)255; return p; };
  float* xf0   = (float*)alloc((size_t)NFACT*H*4);
  float* xf1   = (float*)alloc((size_t)NFACT*H*4);
  float* xc0   = (float*)alloc((size_t)NCOMP*H*4);
  float* xc1   = (float*)alloc((size_t)NCOMP*H*4);
  float* w_f2c = (float*)alloc((size_t)EDGES*4);
  float* w_c2f = (float*)alloc((size_t)EDGES*4);
  int4* ed_f2c = (int4*)alloc((size_t)EDGES*16);
  int4* ed_c2f = (int4*)alloc((size_t)EDGES*16);
  int* off_f2c = (int*)alloc((size_t)(NCOMP+1)*4);
  int* cur_f2c = (int*)alloc((size_t)NCOMP*4);
  int* off_c2f = (int*)alloc((size_t)(NFACT+1)*4);
  int* cur_c2f = (int*)alloc((size_t)NFACT*4);
  int* part    = (int*)alloc(128*4);
  float* pooled= (float*)alloc((size_t)BATCH*256*4);
  _Float16* wt_in = (_Float16*)alloc((size_t)49152*2);
  _Float16* wcat0 = (_Float16*)alloc((size_t)32768*2);
  _Float16* wcat1 = (_Float16*)alloc((size_t)32768*2);

  // --- weight prep (f16 transposed) + edge gates ---
  k_prep<<<448,256,0,stream>>>(W_in_f, W_rel, W_root, wt_in, wcat0, wcat1);
  k_gate<<<512,256,0,stream>>>(ea_f2c, eW1,eb1,eW2,eb2,eW3,eb3, w_f2c, EDGES);
  k_gate<<<512,256,0,stream>>>(ea_c2f, eW1,eb1,eW2,eb2,eW3,eb3, w_c2f, EDGES);

  // --- CSR f2c (dst in comp space) ---
  hipMemsetAsync(cur_f2c, 0, NCOMP*4, stream);
  k_hist<<<512,256,0,stream>>>(dst_f2c, EDGES, cur_f2c);
  {
    int nb = (NCOMP + 1023)/1024;
    k_scan1<<<nb,1024,0,stream>>>(cur_f2c, NCOMP, off_f2c, part);
    k_scan2<<<1,128,0,stream>>>(part, nb);
    k_scan3<<<nb,1024,0,stream>>>(off_f2c, NCOMP, part, EDGES);
  }
  hipMemsetAsync(cur_f2c, 0, NCOMP*4, stream);
  k_fill2<<<512,256,0,stream>>>(s_f2c, dst_f2c, w_f2c, EDGES, off_f2c, cur_f2c, ed_f2c);

  // --- CSR c2f (dst in fact space) ---
  hipMemsetAsync(cur_c2f, 0, NFACT*4, stream);
  k_hist<<<512,256,0,stream>>>(dst_c2f, EDGES, cur_c2f);
  {
    int nb = (NFACT + 1023)/1024;
    k_scan1<<<nb,1024,0,stream>>>(cur_c2f, NFACT, off_c2f, part);
    k_scan2<<<1,128,0,stream>>>(part, nb);
    k_scan3<<<nb,1024,0,stream>>>(off_c2f, NFACT, part, EDGES);
  }
  hipMemsetAsync(cur_c2f, 0, NFACT*4, stream);
  k_fill2<<<512,256,0,stream>>>(s_c2f, dst_c2f, w_c2f, EDGES, off_c2f, cur_c2f, ed_c2f);

  // --- input projections ---
  k_input_m<<<(NFACT/16 + 3)/4,256,0,stream>>>(x_fact, wt_in, b_in_f, xf0);
  k_input_s<64,8><<<NCOMP/8,128,0,stream>>>(x_comp, W_in_c, b_in_c, xc0);

  // --- GNN layers ---
  const float* xf_p = xf0; const float* xc_p = xc0;
  float* xf_n = xf1; float* xc_n = xc1;
  for (int l = 0; l < 2; l++){
    const float* Wr0 = W_rel  + (size_t)(l*2+0)*H*H;
    const float* br0 = b_rel  + (size_t)(l*2+0)*H;
    const float* br1 = b_rel  + (size_t)(l*2+1)*H;
    const float* Wo0 = W_root + (size_t)(l*2+0)*H*H;
    const _Float16* wcat = (l == 0) ? wcat0 : wcat1;
    k_layer<4><<<NCOMP/4,128,0,stream>>>(xf_p, xc_p, off_f2c, ed_f2c,
                                         Wr0, br0, Wo0, ln_s + H, ln_b + H, xc_n);
    k_layer_m<<<NFACT/16,64,0,stream>>>(xc_p, xf_p, off_c2f, ed_c2f,
                                        wcat, br1, ln_s, ln_b, xf_n);
    const float* tf = xf_p; xf_p = xf_n; xf_n = (float*)tf;
    const float* tc = xc_p; xc_p = xc_n; xc_n = (float*)tc;
  }

  // --- pooling + head ---
  hipMemsetAsync(pooled, 0, (size_t)BATCH*256*4, stream);
  k_pool_acc<<<FBLK + CBLK,128,0,stream>>>(xf_p, xc_p, fb, cb, pooled);
  k_head<<<BATCH,128,0,stream>>>(pooled, fb, cb, Wc1, bc1, Wc2, bc2, out);
}